// Round 5
// baseline (563.479 us; speedup 1.0000x reference)
//
#include <hip/hip_runtime.h>
#include <math.h>

#define BS 32
#define S  2048
#define H  1024

// native clang vector type — required for __builtin_nontemporal_load
typedef float vfloat4 __attribute__((ext_vector_type(4)));

// ---------------------------------------------------------------------------
// Kernel 1: v[b,h] = sum_k hidden[b,k] * W[k,h]   (v = hidden @ W)
// grid (H/64, BS) = 512 blocks, block 256 = 4 waves.
// Split-k across waves; LDS combine. Also zeroes the 32 per-row completion
// counters used by the fused softmax (d_ws is poisoned 0xAA each iteration).
// ---------------------------------------------------------------------------
__global__ __launch_bounds__(256) void compute_v(const float* __restrict__ hidden,
                                                 const float* __restrict__ W,
                                                 float* __restrict__ v,
                                                 int* __restrict__ counters) {
    __shared__ float hid[H];
    __shared__ float part[4][64];
    const int b    = blockIdx.y;
    const int tid  = threadIdx.x;
    const int wave = tid >> 6;
    const int lane = tid & 63;

    if (blockIdx.x == 0 && blockIdx.y == 0 && tid < BS)
        counters[tid] = 0;

    ((float4*)hid)[tid] = ((const float4*)(hidden + b * H))[tid];
    __syncthreads();

    const int h = blockIdx.x * 64 + lane;
    const float* Wp = W + (size_t)(wave * 256) * H + h;
    const float* hp = hid + wave * 256;
    float acc = 0.f;
#pragma unroll 8
    for (int k = 0; k < 256; ++k)
        acc = fmaf(Wp[(size_t)k * H], hp[k], acc);

    part[wave][lane] = acc;
    __syncthreads();
    if (wave == 0) {
        float r = (part[0][lane] + part[1][lane]) + (part[2][lane] + part[3][lane]);
        v[b * H + h] = r;
    }
}

// ---------------------------------------------------------------------------
// Kernel 2 (fused): scores[b,s] = dot(enc[b,s,:], v[b,:]); the last block to
// finish a row softmaxes it in place.
// grid (S/64, BS) = 1024 blocks, block 256 (4 waves), 16 rows/wave in groups
// of 4 (round-3 best config: nt loads, 4 pipelined shuffle-reduce chains).
// Bias omitted: constant per softmax row, cancels in softmax.
// ---------------------------------------------------------------------------
__global__ __launch_bounds__(256) void compute_scores_softmax(
        const float* __restrict__ enc,
        const float* __restrict__ v,
        float* __restrict__ scores,
        int* __restrict__ counters) {
    const int b    = blockIdx.y;
    const int tid  = threadIdx.x;
    const int wave = tid >> 6;
    const int lane = tid & 63;

    const float4* v4 = (const float4*)(v + b * H);
    float4 vr[4];
#pragma unroll
    for (int it = 0; it < 4; ++it) vr[it] = v4[it * 64 + lane];

    const int s0 = blockIdx.x * 64 + wave * 16;
    const vfloat4* encb = (const vfloat4*)enc + (size_t)b * S * (H / 4);

#pragma unroll
    for (int i = 0; i < 16; i += 4) {
        float acc[4] = {0.f, 0.f, 0.f, 0.f};
#pragma unroll
        for (int j = 0; j < 4; ++j) {
            const vfloat4* e4 = encb + (size_t)(s0 + i + j) * (H / 4);
#pragma unroll
            for (int it = 0; it < 4; ++it) {
                vfloat4 e = __builtin_nontemporal_load(&e4[it * 64 + lane]);
                acc[j] = fmaf(e.x, vr[it].x, acc[j]);
                acc[j] = fmaf(e.y, vr[it].y, acc[j]);
                acc[j] = fmaf(e.z, vr[it].z, acc[j]);
                acc[j] = fmaf(e.w, vr[it].w, acc[j]);
            }
        }
#pragma unroll
        for (int off = 32; off > 0; off >>= 1) {
#pragma unroll
            for (int j = 0; j < 4; ++j)
                acc[j] += __shfl_xor(acc[j], off, 64);
        }
        if (lane < 4)
            scores[b * S + s0 + i + lane] = acc[lane];
    }

    // ---- last block for row b performs the softmax in place ----
    __threadfence();                       // release: score stores visible device-wide
    __shared__ int is_last;
    if (tid == 0) {
        int old = atomicAdd(&counters[b], 1);
        is_last = (old == (S / 64) - 1);
    }
    __syncthreads();
    if (!is_last) return;
    __threadfence();                       // acquire: see other blocks' stores

    __shared__ float red[4];
    float4* row4 = (float4*)(scores + b * S);
    float4 x[2];
    float m = -INFINITY;
#pragma unroll
    for (int i = 0; i < 2; ++i) {
        x[i] = row4[tid + i * 256];
        m = fmaxf(m, fmaxf(fmaxf(x[i].x, x[i].y), fmaxf(x[i].z, x[i].w)));
    }
#pragma unroll
    for (int off = 1; off < 64; off <<= 1)
        m = fmaxf(m, __shfl_xor(m, off, 64));
    if (lane == 0) red[wave] = m;
    __syncthreads();
    m = fmaxf(fmaxf(red[0], red[1]), fmaxf(red[2], red[3]));

    float sum = 0.f;
#pragma unroll
    for (int i = 0; i < 2; ++i) {
        x[i].x = __expf(x[i].x - m);
        x[i].y = __expf(x[i].y - m);
        x[i].z = __expf(x[i].z - m);
        x[i].w = __expf(x[i].w - m);
        sum += (x[i].x + x[i].y) + (x[i].z + x[i].w);
    }
#pragma unroll
    for (int off = 1; off < 64; off <<= 1)
        sum += __shfl_xor(sum, off, 64);
    __syncthreads();   // red[] reuse
    if (lane == 0) red[wave] = sum;
    __syncthreads();
    sum = (red[0] + red[1]) + (red[2] + red[3]);
    const float inv = 1.0f / sum;

#pragma unroll
    for (int i = 0; i < 2; ++i) {
        x[i].x *= inv; x[i].y *= inv; x[i].z *= inv; x[i].w *= inv;
        row4[tid + i * 256] = x[i];
    }
}

extern "C" void kernel_launch(void* const* d_in, const int* in_sizes, int n_in,
                              void* d_out, int out_size, void* d_ws, size_t ws_size,
                              hipStream_t stream) {
    const float* hidden = (const float*)d_in[0];   // [BS, H]
    const float* enc    = (const float*)d_in[1];   // [BS, S, H]
    const float* W      = (const float*)d_in[2];   // [H, H]
    // d_in[3] = bias: unused — cancels in the softmax.

    float* v        = (float*)d_ws;                 // BS*H floats = 128 KiB
    int*   counters = (int*)((char*)d_ws + BS * H * sizeof(float));
    float* outp     = (float*)d_out;                // BS*S floats

    dim3 g1(H / 64, BS);
    compute_v<<<g1, 256, 0, stream>>>(hidden, W, v, counters);

    dim3 g2(S / 64, BS);
    compute_scores_softmax<<<g2, 256, 0, stream>>>(enc, v, outp, counters);
}

// Round 6
// 362.090 us; speedup vs baseline: 1.5562x; 1.5562x over previous
//
#include <hip/hip_runtime.h>
#include <math.h>

#define BS 32
#define S  2048
#define H  1024

// native clang vector type — required for __builtin_nontemporal_load
typedef float vfloat4 __attribute__((ext_vector_type(4)));

// ---------------------------------------------------------------------------
// Kernel 1: v[b,h] = sum_k hidden[b,k] * W[k,h]   (v = hidden @ W)
// grid (H/64, BS) = 512 blocks, block 256 = 4 waves.
// Split-k across waves; LDS combine. W (4 MiB) is L2/LLC-resident.
// ---------------------------------------------------------------------------
__global__ __launch_bounds__(256) void compute_v(const float* __restrict__ hidden,
                                                 const float* __restrict__ W,
                                                 float* __restrict__ v) {
    __shared__ float hid[H];
    __shared__ float part[4][64];
    const int b    = blockIdx.y;
    const int tid  = threadIdx.x;
    const int wave = tid >> 6;
    const int lane = tid & 63;

    ((float4*)hid)[tid] = ((const float4*)(hidden + b * H))[tid];
    __syncthreads();

    const int h = blockIdx.x * 64 + lane;
    const float* Wp = W + (size_t)(wave * 256) * H + h;
    const float* hp = hid + wave * 256;
    float acc = 0.f;
#pragma unroll 8
    for (int k = 0; k < 256; ++k)
        acc = fmaf(Wp[(size_t)k * H], hp[k], acc);

    part[wave][lane] = acc;
    __syncthreads();
    if (wave == 0) {
        float r = (part[0][lane] + part[1][lane]) + (part[2][lane] + part[3][lane]);
        v[b * H + h] = r;
    }
}

// ---------------------------------------------------------------------------
// Kernel 2: scores[b,s] = dot(enc[b,s,:], v[b,:])
// grid (S/16, BS) = 4096 blocks, block 256 (4 waves), 4 rows per wave.
// 16384 waves = 2x the device's 8192 wave slots -> occupancy-driven latency
// hiding (round-5 rocprof: 1024-block version was latency-bound at 27% occ,
// 512 GB/s). Each wave: 16 nt float4 loads in flight, 4 pipelined
// shuffle-reduce chains, 4 stores, exit.
// Bias omitted: constant per softmax row, cancels in softmax.
// ---------------------------------------------------------------------------
__global__ __launch_bounds__(256) void compute_scores(const float* __restrict__ enc,
                                                      const float* __restrict__ v,
                                                      float* __restrict__ scores) {
    const int b    = blockIdx.y;
    const int tid  = threadIdx.x;
    const int wave = tid >> 6;
    const int lane = tid & 63;

    const float4* v4 = (const float4*)(v + b * H);
    float4 vr[4];
#pragma unroll
    for (int it = 0; it < 4; ++it) vr[it] = v4[it * 64 + lane];

    const int s0 = blockIdx.x * 16 + wave * 4;
    const vfloat4* encb = (const vfloat4*)enc + (size_t)b * S * (H / 4);

    float acc[4] = {0.f, 0.f, 0.f, 0.f};
#pragma unroll
    for (int j = 0; j < 4; ++j) {
        const vfloat4* e4 = encb + (size_t)(s0 + j) * (H / 4);
#pragma unroll
        for (int it = 0; it < 4; ++it) {
            vfloat4 e = __builtin_nontemporal_load(&e4[it * 64 + lane]);
            acc[j] = fmaf(e.x, vr[it].x, acc[j]);
            acc[j] = fmaf(e.y, vr[it].y, acc[j]);
            acc[j] = fmaf(e.z, vr[it].z, acc[j]);
            acc[j] = fmaf(e.w, vr[it].w, acc[j]);
        }
    }
    // four independent 64-lane butterfly reductions — chains pipeline
#pragma unroll
    for (int off = 32; off > 0; off >>= 1) {
#pragma unroll
        for (int j = 0; j < 4; ++j)
            acc[j] += __shfl_xor(acc[j], off, 64);
    }
    if (lane < 4)
        scores[b * S + s0 + lane] = acc[lane];
}

// ---------------------------------------------------------------------------
// Kernel 3: in-place row softmax on scores (= d_out). grid BS, block 256,
// float4 I/O (2 float4 per thread).
// ---------------------------------------------------------------------------
__global__ __launch_bounds__(256) void softmax_rows(float* __restrict__ scores) {
    const int b    = blockIdx.x;
    const int tid  = threadIdx.x;
    const int wave = tid >> 6;
    const int lane = tid & 63;
    __shared__ float red[4];

    float4* row4 = (float4*)(scores + b * S);
    float4 x[2];
    float m = -INFINITY;
#pragma unroll
    for (int i = 0; i < 2; ++i) {
        x[i] = row4[tid + i * 256];
        m = fmaxf(m, fmaxf(fmaxf(x[i].x, x[i].y), fmaxf(x[i].z, x[i].w)));
    }
#pragma unroll
    for (int off = 1; off < 64; off <<= 1)
        m = fmaxf(m, __shfl_xor(m, off, 64));
    if (lane == 0) red[wave] = m;
    __syncthreads();
    m = fmaxf(fmaxf(red[0], red[1]), fmaxf(red[2], red[3]));

    float sum = 0.f;
#pragma unroll
    for (int i = 0; i < 2; ++i) {
        x[i].x = __expf(x[i].x - m);
        x[i].y = __expf(x[i].y - m);
        x[i].z = __expf(x[i].z - m);
        x[i].w = __expf(x[i].w - m);
        sum += (x[i].x + x[i].y) + (x[i].z + x[i].w);
    }
#pragma unroll
    for (int off = 1; off < 64; off <<= 1)
        sum += __shfl_xor(sum, off, 64);
    __syncthreads();   // red[] reuse
    if (lane == 0) red[wave] = sum;
    __syncthreads();
    sum = (red[0] + red[1]) + (red[2] + red[3]);
    const float inv = 1.0f / sum;

#pragma unroll
    for (int i = 0; i < 2; ++i) {
        x[i].x *= inv; x[i].y *= inv; x[i].z *= inv; x[i].w *= inv;
        row4[tid + i * 256] = x[i];
    }
}

extern "C" void kernel_launch(void* const* d_in, const int* in_sizes, int n_in,
                              void* d_out, int out_size, void* d_ws, size_t ws_size,
                              hipStream_t stream) {
    const float* hidden = (const float*)d_in[0];   // [BS, H]
    const float* enc    = (const float*)d_in[1];   // [BS, S, H]
    const float* W      = (const float*)d_in[2];   // [H, H]
    // d_in[3] = bias: unused — cancels in the softmax.

    float* v    = (float*)d_ws;    // BS*H floats = 128 KiB scratch
    float* outp = (float*)d_out;   // BS*S floats; scores then softmax in place

    dim3 g1(H / 64, BS);
    compute_v<<<g1, 256, 0, stream>>>(hidden, W, v);

    dim3 g2(S / 16, BS);
    compute_scores<<<g2, 256, 0, stream>>>(enc, v, outp);

    softmax_rows<<<BS, 256, 0, stream>>>(outp);
}